// Round 2
// baseline (166.645 us; speedup 1.0000x reference)
//
#include <hip/hip_runtime.h>
#include <math.h>

#define G   50
#define T   24
#define B   128
#define NLP (B * T)
#define SZ  (B * G * T)   // 153600 elements per (B,G,T) output

// d_out layout (floats, concatenated in return order):
//   [0,      SZ)        P_DA   (B,G,T)
//   [SZ,     2SZ)       R_up
//   [2SZ,    3SZ)       R_dn
//   [3SZ,    3SZ+B)     obj    (B,)
//   [3SZ+B,  4SZ+B)     Cost_DA

// DPP helper (cold paths): row_ror rotate within 16-lane rows.
template <int CTRL>
__device__ __forceinline__ float dpp_mov(float x) {
    int r = __builtin_amdgcn_update_dpp(0, __float_as_int(x), CTRL, 0xf, 0xf, true);
    return __int_as_float(r);
}

__device__ __forceinline__ float row_sum1(float a) {
    a += dpp_mov<0x121>(a);
    a += dpp_mov<0x122>(a);
    a += dpp_mov<0x124>(a);
    a += dpp_mov<0x128>(a);
    return a;
}

// Full-wave (64-lane) all-reduce of 3 values, results broadcast via SGPR.
// 4x row_ror stages -> every lane has its 16-row sum; row_bcast:15 (rows 1,3)
// and row_bcast:31 (rows 2,3) fold rows; lane 63 holds the total, v_readlane
// moves it to an SGPR (uniform across the wave -- the whole wave is one LP).
// Pure VALU pipe: no LDS latency on the iteration-critical path.
// 3 chains interleaved => every DPP/readlane has >=2 intervening instructions
// (2-wait-state VALU->DPP hazard). s_nop 1 guards the compiler-emitted
// producers immediately preceding the block.
__device__ __forceinline__ void wave_sum3(float& a, float& b, float& c,
                                          float& ta, float& tb, float& tc) {
    asm("s_nop 1\n\t"
        "v_add_f32_dpp %0, %0, %0 row_ror:1 row_mask:0xf bank_mask:0xf\n\t"
        "v_add_f32_dpp %1, %1, %1 row_ror:1 row_mask:0xf bank_mask:0xf\n\t"
        "v_add_f32_dpp %2, %2, %2 row_ror:1 row_mask:0xf bank_mask:0xf\n\t"
        "v_add_f32_dpp %0, %0, %0 row_ror:2 row_mask:0xf bank_mask:0xf\n\t"
        "v_add_f32_dpp %1, %1, %1 row_ror:2 row_mask:0xf bank_mask:0xf\n\t"
        "v_add_f32_dpp %2, %2, %2 row_ror:2 row_mask:0xf bank_mask:0xf\n\t"
        "v_add_f32_dpp %0, %0, %0 row_ror:4 row_mask:0xf bank_mask:0xf\n\t"
        "v_add_f32_dpp %1, %1, %1 row_ror:4 row_mask:0xf bank_mask:0xf\n\t"
        "v_add_f32_dpp %2, %2, %2 row_ror:4 row_mask:0xf bank_mask:0xf\n\t"
        "v_add_f32_dpp %0, %0, %0 row_ror:8 row_mask:0xf bank_mask:0xf\n\t"
        "v_add_f32_dpp %1, %1, %1 row_ror:8 row_mask:0xf bank_mask:0xf\n\t"
        "v_add_f32_dpp %2, %2, %2 row_ror:8 row_mask:0xf bank_mask:0xf\n\t"
        "v_add_f32_dpp %0, %0, %0 row_bcast:15 row_mask:0xa bank_mask:0xf\n\t"
        "v_add_f32_dpp %1, %1, %1 row_bcast:15 row_mask:0xa bank_mask:0xf\n\t"
        "v_add_f32_dpp %2, %2, %2 row_bcast:15 row_mask:0xa bank_mask:0xf\n\t"
        "v_add_f32_dpp %0, %0, %0 row_bcast:31 row_mask:0xc bank_mask:0xf\n\t"
        "v_add_f32_dpp %1, %1, %1 row_bcast:31 row_mask:0xc bank_mask:0xf\n\t"
        "v_add_f32_dpp %2, %2, %2 row_bcast:31 row_mask:0xc bank_mask:0xf\n\t"
        "v_readlane_b32 %3, %0, 63\n\t"
        "v_readlane_b32 %4, %1, 63\n\t"
        "v_readlane_b32 %5, %2, 63"
        : "+v"(a), "+v"(b), "+v"(c), "=s"(ta), "=s"(tb), "=s"(tc));
}

// Cold-path full-wave sum, result uniform (via SGPR).
__device__ __forceinline__ float wave_sum1(float a) {
    float s;
    asm("s_nop 1\n\t"
        "v_add_f32_dpp %0, %0, %0 row_ror:1 row_mask:0xf bank_mask:0xf\n\t"
        "s_nop 1\n\t"
        "v_add_f32_dpp %0, %0, %0 row_ror:2 row_mask:0xf bank_mask:0xf\n\t"
        "s_nop 1\n\t"
        "v_add_f32_dpp %0, %0, %0 row_ror:4 row_mask:0xf bank_mask:0xf\n\t"
        "s_nop 1\n\t"
        "v_add_f32_dpp %0, %0, %0 row_ror:8 row_mask:0xf bank_mask:0xf\n\t"
        "s_nop 1\n\t"
        "v_add_f32_dpp %0, %0, %0 row_bcast:15 row_mask:0xa bank_mask:0xf\n\t"
        "s_nop 1\n\t"
        "v_add_f32_dpp %0, %0, %0 row_bcast:31 row_mask:0xc bank_mask:0xf\n\t"
        "s_nop 1\n\t"
        "v_readlane_b32 %1, %0, 63"
        : "+v"(a), "=s"(s));
    return s;
}

// One wave per block solves ONE LP. Lane l owns generator g = l (valid iff
// l < 50). Sentinel cost BIG clamps invalid slots' primal vars to 0 so they
// contribute nothing to the wave sums. All coupling scalars (z0, zru, zrd)
// are wave-uniform.
__global__ __launch_bounds__(64)
void pdhg_lp_kernel(const float* __restrict__ forecast,
                    const float* __restrict__ pmin,
                    const float* __restrict__ pmax,
                    const float* __restrict__ bcost,
                    const float* __restrict__ ccost,
                    const int*   __restrict__ n_iters_p,
                    float* __restrict__ out,
                    float* __restrict__ ws_partial,   // NLP floats (or null)
                    float tau)
{
    const int lane = threadIdx.x;         // 0..63
    const int lp   = blockIdx.x;
    const int b    = lp / T;
    const int t    = lp - b * T;
    const int n_iters = n_iters_p[0];

    const int  g  = lane;                 // one generator per lane
    const bool vg = (lane < G);

    const float bj  = vg ? bcost[g] : 0.f;
    const float cj  = vg ? ccost[g] : 0.f;
    const float pmx = vg ? pmax[g]  : 0.f;
    const float pmn = vg ? pmin[g]  : 0.f;
    const float f = forecast[lp];         // uniform within the wave

    const float ts  = tau * tau;          // sigma == tau
    const float BIG = 1e30f;              // sentinel: clamps invalid slot to 0

    const float tcP  = vg ? (tau * bj)         : BIG;
    const float tcRu = vg ? (tau * 0.05f * bj) : BIG;
    const float tcRd = vg ? (tau * 0.02f * bj) : BIG;
    const float tspmx = ts * pmx, tspmn = ts * pmn;
    const float tsf   = ts * f;
    const float tsreq = ts * 0.02f * f;   // REQ_UP_RATIO == REQ_DN_RATIO

    float P = 0.f, Ru = 0.f, Rd = 0.f;
    float z1 = 0.f, z2 = 0.f, z3 = 0.f, z4 = 0.f;  // scaled duals tau*y
    float z0 = 0.f, zru = 0.f, zrd = 0.f;          // wave-uniform

    for (int it = 0; it < n_iters; ++it) {
        // ---- x-update: x_new = max(x - (tau*c + tau*K^T y), 0) ----
        float gP  = (z1 - z2) + (z3 - z4) + z0;
        float Pn  = fmaxf(P  - tcP  - gP, 0.f);
        float Run = fmaxf(Ru - tcRu - (z1 - zru), 0.f);
        float Rdn = fmaxf(Rd - tcRd - (z2 - zrd), 0.f);

        // overrelaxation: x_bar = 2*x_new - x_old
        float Pb  = 2.f * Pn  - P;
        float Rub = 2.f * Run - Ru;
        float Rdb = 2.f * Rdn - Rd;
        P = Pn; Ru = Run; Rd = Rdn;

        // ---- full-wave sums over generators (VALU-only DPP tree) ----
        float sP = Pb, sRu = Rub, sRd = Rdb;
        float tP, tRu, tRd;
        wave_sum3(sP, sRu, sRd, tP, tRu, tRd);

        // ---- z-update: z += tau*sigma*(K x_bar - q), clamp ineq rows ----
        z1 = fmaxf(z1 + ts * (Pb + Rub) - tspmx, 0.f);   // P+Ru <= pmax
        z2 = fmaxf(z2 + ts * (Rdb - Pb) + tspmn, 0.f);   // -P+Rd <= -pmin
        z3 = fmaxf(z3 + ts * Pb - tspmx, 0.f);           // P <= pmax
        z4 = fmaxf(z4 - ts * Pb + tspmn, 0.f);           // -P <= -pmin
        z0  = z0 + ts * tP - tsf;                        // equality row
        zru = fmaxf(zru + tsreq - ts * tRu, 0.f);        // -sum Ru <= -req
        zrd = fmaxf(zrd + tsreq - ts * tRd, 0.f);        // -sum Rd <= -req
    }

    const float cost = bj * P + cj;
    if (vg) {
        const int a0 = b * (G * T) + t + g * T;
        out[a0] = P;  out[SZ + a0] = Ru;  out[2*SZ + a0] = Rd;  out[3*SZ + B + a0] = cost;
    }

    if (ws_partial) {
        // per-(b,t) objective partial: sum_g cost + 0.05*b*Ru + 0.02*b*Rd
        float lo = cost + (0.05f * bj) * Ru + (0.02f * bj) * Rd;
        float tot = wave_sum1(lo);
        if (lane == 0) ws_partial[lp] = tot;
    }
}

// obj[b] = sum_t ws_partial[b*T + t]   (deterministic, tiny)
__global__ __launch_bounds__(64)
void obj_final_kernel(const float* __restrict__ ws_partial, float* __restrict__ out)
{
    const int b = blockIdx.x * 64 + threadIdx.x;
    if (b < B) {
        float s = 0.f;
        #pragma unroll
        for (int t = 0; t < T; ++t) s += ws_partial[b * T + t];
        out[3 * SZ + b] = s;
    }
}

// Fallback (ws too small): recompute obj from outputs, one block per b
__global__ __launch_bounds__(256)
void obj_kernel(const float* __restrict__ bcost, float* __restrict__ out)
{
    const int b = blockIdx.x;
    const float* Ru = out + SZ     + (size_t)b * (G * T);
    const float* Rd = out + 2 * SZ + (size_t)b * (G * T);
    const float* C  = out + 3 * SZ + B + (size_t)b * (G * T);

    float s = 0.f;
    for (int i = threadIdx.x; i < G * T; i += 256) {
        const int g = i / T;
        const float bg = bcost[g];
        s += C[i] + 0.05f * bg * Ru[i] + 0.02f * bg * Rd[i];
    }
    __shared__ float sm[16];
    s = row_sum1(s);                                 // 16-lane row sums
    if ((threadIdx.x & 15) == 0) sm[threadIdx.x >> 4] = s;
    __syncthreads();
    if (threadIdx.x == 0) {
        float tot = 0.f;
        #pragma unroll
        for (int i = 0; i < 16; ++i) tot += sm[i];
        out[3 * SZ + b] = tot;
    }
}

extern "C" void kernel_launch(void* const* d_in, const int* in_sizes, int n_in,
                              void* d_out, int out_size, void* d_ws, size_t ws_size,
                              hipStream_t stream) {
    const float* forecast = (const float*)d_in[0];
    const float* pmin_p   = (const float*)d_in[1];
    const float* pmax_p   = (const float*)d_in[2];
    const float* b_p      = (const float*)d_in[3];
    const float* c_p      = (const float*)d_in[4];
    const int*   niter_p  = (const int*)  d_in[5];
    float* out = (float*)d_out;

    // ||K||_2 analytic for this fixed 0/±1 structure (G=50):
    // K^T K = [[4I+J, I, -I],[I, I+J, 0],[-I, 0, I+J]]; largest eig on the
    // ones-subspace is (105+sqrt(17))/2  ->  L = sqrt((105+sqrt(17))/2)
    const double L = sqrt((105.0 + sqrt(17.0)) * 0.5);
    const float tau = (float)(0.9 / L);   // sigma == tau

    const bool use_ws = (ws_size >= (size_t)NLP * sizeof(float));
    float* wsp = use_ws ? (float*)d_ws : nullptr;

    // 64 lanes per LP, one LP per wave -> 3072 waves (3/SIMD), vs 1536/768 before
    pdhg_lp_kernel<<<NLP, 64, 0, stream>>>(forecast, pmin_p, pmax_p,
                                           b_p, c_p, niter_p, out, wsp, tau);
    if (use_ws) {
        obj_final_kernel<<<(B + 63) / 64, 64, 0, stream>>>(wsp, out);
    } else {
        obj_kernel<<<B, 256, 0, stream>>>(b_p, out);
    }
}

// Round 3
// 136.394 us; speedup vs baseline: 1.2218x; 1.2218x over previous
//
#include <hip/hip_runtime.h>
#include <math.h>

#define G   50
#define T   24
#define B   128
#define NLP (B * T)
#define SZ  (B * G * T)   // 153600 elements per (B,G,T) output

typedef float v2f __attribute__((ext_vector_type(2)));

// d_out layout (floats, concatenated in return order):
//   [0,      SZ)        P_DA   (B,G,T)
//   [SZ,     2SZ)       R_up
//   [2SZ,    3SZ)       R_dn
//   [3SZ,    3SZ+B)     obj    (B,)
//   [3SZ+B,  4SZ+B)     Cost_DA

__device__ __forceinline__ v2f vmax0(v2f v) {
    v2f z = {0.f, 0.f};
    return __builtin_elementwise_max(v, z);
}

// DPP helper (cold paths): row_ror rotate within 16-lane rows.
template <int CTRL>
__device__ __forceinline__ float dpp_mov(float x) {
    int r = __builtin_amdgcn_update_dpp(0, __float_as_int(x), CTRL, 0xf, 0xf, true);
    return __int_as_float(r);
}

__device__ __forceinline__ float row_sum1(float a) {
    a += dpp_mov<0x121>(a);
    a += dpp_mov<0x122>(a);
    a += dpp_mov<0x124>(a);
    a += dpp_mov<0x128>(a);
    return a;
}

// Staged 16-lane-row reduce: one ror-stage per asm block (3 interleaved
// chains), so the compiler can schedule independent z-update v_pk_* work
// BETWEEN stages to fill DPP latency/hazard slots.
// Hazard audit: within a block, each chain's DPP has 2 intervening
// instructions before its next DPP read (2-wait-state VALU->DPP rule).
// Across adjacent blocks with NO filler: value %0 is written by instr 1 of
// block k and DPP-read by instr 1 of block k+1 -> instrs 2,3 of block k
// intervene = 2 wait states, safe by construction. s_nop 1 in the FIRST
// stage guards the compiler-emitted producers immediately preceding.
#define DPP_STAGE_FIRST(a, b, c)                                              \
    asm("s_nop 1\n\t"                                                         \
        "v_add_f32_dpp %0, %0, %0 row_ror:1 row_mask:0xf bank_mask:0xf\n\t"   \
        "v_add_f32_dpp %1, %1, %1 row_ror:1 row_mask:0xf bank_mask:0xf\n\t"   \
        "v_add_f32_dpp %2, %2, %2 row_ror:1 row_mask:0xf bank_mask:0xf"       \
        : "+v"(a), "+v"(b), "+v"(c))

#define DPP_STAGE(a, b, c, R)                                                 \
    asm("v_add_f32_dpp %0, %0, %0 row_ror:" #R " row_mask:0xf bank_mask:0xf\n\t" \
        "v_add_f32_dpp %1, %1, %1 row_ror:" #R " row_mask:0xf bank_mask:0xf\n\t" \
        "v_add_f32_dpp %2, %2, %2 row_ror:" #R " row_mask:0xf bank_mask:0xf"     \
        : "+v"(a), "+v"(b), "+v"(c))

// One wave per block; row r = lane>>4 (16 lanes) solves LP (4*blockIdx + r).
// Each lane owns generators {lh, lh+16} (v2f A) and {lh+32, lh+48} (v2f B;
// B.y valid iff lh<2). 50 gens total, sentinel cost clamps invalid slots.
__global__ __launch_bounds__(64)
void pdhg_lp_kernel(const float* __restrict__ forecast,
                    const float* __restrict__ pmin,
                    const float* __restrict__ pmax,
                    const float* __restrict__ bcost,
                    const float* __restrict__ ccost,
                    const int*   __restrict__ n_iters_p,
                    float* __restrict__ out,
                    float* __restrict__ ws_partial,   // NLP floats (or null)
                    float tau)
{
    const int lane = threadIdx.x;         // 0..63
    const int lh   = lane & 15;           // lane within row
    const int row  = lane >> 4;           // LP slot within wave
    const int lp   = blockIdx.x * 4 + row;
    const int b    = lp / T;
    const int t    = lp - b * T;
    const int n_iters = n_iters_p[0];

    const int  gA0 = lh,      gA1 = lh + 16;   // always < 50
    const int  gB0 = lh + 32;                  // always < 50
    const int  gB1 = lh + 48;                  // valid iff lh < 2
    const bool vB1 = (lh < 2);

    v2f bjA  = { bcost[gA0], bcost[gA1] };
    v2f bjB  = { bcost[gB0], vB1 ? bcost[gB1] : 0.f };
    v2f cjA  = { ccost[gA0], ccost[gA1] };
    v2f cjB  = { ccost[gB0], vB1 ? ccost[gB1] : 0.f };
    v2f pmxA = { pmax[gA0],  pmax[gA1] };
    v2f pmxB = { pmax[gB0],  vB1 ? pmax[gB1] : 0.f };
    v2f pmnA = { pmin[gA0],  pmin[gA1] };
    v2f pmnB = { pmin[gB0],  vB1 ? pmin[gB1] : 0.f };
    const float f = forecast[lp];         // uniform within each row

    const float ts  = tau * tau;          // sigma == tau
    const float BIG = 1e30f;              // sentinel: clamps invalid slot to 0

    v2f tcPA  = tau * bjA;
    v2f tcPB  = tau * bjB;           if (!vB1) tcPB.y  = BIG;
    v2f tcRuA = (tau * 0.05f) * bjA;
    v2f tcRuB = (tau * 0.05f) * bjB; if (!vB1) tcRuB.y = BIG;
    v2f tcRdA = (tau * 0.02f) * bjA;
    v2f tcRdB = (tau * 0.02f) * bjB; if (!vB1) tcRdB.y = BIG;
    v2f tspmxA = ts * pmxA, tspmxB = ts * pmxB;
    v2f tspmnA = ts * pmnA, tspmnB = ts * pmnB;
    const float tsf   = ts * f;
    const float tsreq = ts * 0.02f * f;   // REQ_UP_RATIO == REQ_DN_RATIO

    v2f PA = {0,0}, PB = {0,0}, RuA = {0,0}, RuB = {0,0}, RdA = {0,0}, RdB = {0,0};
    v2f z1A = {0,0}, z1B = {0,0}, z2A = {0,0}, z2B = {0,0};
    v2f z3A = {0,0}, z3B = {0,0}, z4A = {0,0}, z4B = {0,0};   // scaled duals tau*y
    float z0 = 0.f, zru = 0.f, zrd = 0.f;                     // row-uniform

    for (int it = 0; it < n_iters; ++it) {
        // ---- x-update: x_new = max(x - (tau*c + tau*K^T y), 0) ----
        v2f z0v  = { z0,  z0  };
        v2f zruv = { zru, zru };
        v2f zrdv = { zrd, zrd };
        v2f gPA = (z1A - z2A) + (z3A - z4A) + z0v;
        v2f gPB = (z1B - z2B) + (z3B - z4B) + z0v;
        v2f PnA = vmax0(PA - tcPA - gPA);
        v2f PnB = vmax0(PB - tcPB - gPB);
        v2f RunA = vmax0(RuA - tcRuA - z1A + zruv);
        v2f RunB = vmax0(RuB - tcRuB - z1B + zruv);
        v2f RdnA = vmax0(RdA - tcRdA - z2A + zrdv);
        v2f RdnB = vmax0(RdB - tcRdB - z2B + zrdv);

        // overrelaxation: x_bar = 2*x_new - x_old
        v2f PbA  = 2.f * PnA  - PA,  PbB  = 2.f * PnB  - PB;
        v2f RubA = 2.f * RunA - RuA, RubB = 2.f * RunB - RuB;
        v2f RdbA = 2.f * RdnA - RdA, RdbB = 2.f * RdnB - RdB;
        PA = PnA; PB = PnB; RuA = RunA; RuB = RunB; RdA = RdnA; RdB = RdnB;

        // ---- row-local sum preparation ----
        v2f tP = PbA + PbB, tRu = RubA + RubB, tRd = RdbA + RdbB;
        float sP  = tP.x  + tP.y;
        float sRu = tRu.x + tRu.y;
        float sRd = tRd.x + tRd.y;

        // shared dual-update terms: e = ts*Pb - ts*pmax, h = ts*pmin - ts*Pb
        v2f eA = ts * PbA - tspmxA;
        v2f hA = tspmnA - ts * PbA;
        v2f eB = ts * PbB - tspmxB;
        v2f hB = tspmnB - ts * PbB;

        // ---- staged DPP reduce, z-updates interleaved into the stages ----
        DPP_STAGE_FIRST(sP, sRu, sRd);                   // ror:1
        z3A = vmax0(z3A + eA);                           // P <= pmax
        z3B = vmax0(z3B + eB);
        z4A = vmax0(z4A + hA);                           // -P <= -pmin
        z4B = vmax0(z4B + hB);
        DPP_STAGE(sP, sRu, sRd, 2);
        z1A = vmax0(z1A + (eA + ts * RubA));             // P+Ru <= pmax
        z2A = vmax0(z2A + (hA + ts * RdbA));             // -P+Rd <= -pmin
        DPP_STAGE(sP, sRu, sRd, 4);
        z1B = vmax0(z1B + (eB + ts * RubB));
        z2B = vmax0(z2B + (hB + ts * RdbB));
        DPP_STAGE(sP, sRu, sRd, 8);

        // ---- row-uniform scalar duals (depend on completed sums) ----
        z0  = z0 + ts * sP - tsf;                        // equality row
        zru = fmaxf(zru + tsreq - ts * sRu, 0.f);        // -sum Ru <= -req
        zrd = fmaxf(zrd + tsreq - ts * sRd, 0.f);        // -sum Rd <= -req
    }

    const v2f costA = bjA * PA + cjA;
    const v2f costB = bjB * PB + cjB;
    {
        const int bgt = b * (G * T) + t;
        const int a0 = bgt + gA0 * T, a1 = bgt + gA1 * T, b0 = bgt + gB0 * T;
        out[a0] = PA.x;  out[SZ + a0] = RuA.x;  out[2*SZ + a0] = RdA.x;  out[3*SZ + B + a0] = costA.x;
        out[a1] = PA.y;  out[SZ + a1] = RuA.y;  out[2*SZ + a1] = RdA.y;  out[3*SZ + B + a1] = costA.y;
        out[b0] = PB.x;  out[SZ + b0] = RuB.x;  out[2*SZ + b0] = RdB.x;  out[3*SZ + B + b0] = costB.x;
        if (vB1) {
            const int b1 = bgt + gB1 * T;
            out[b1] = PB.y;  out[SZ + b1] = RuB.y;  out[2*SZ + b1] = RdB.y;  out[3*SZ + B + b1] = costB.y;
        }
    }

    if (ws_partial) {
        // per-(b,t) objective partial: sum_g cost + 0.05*b*Ru + 0.02*b*Rd
        v2f lo = costA + (0.05f * bjA) * RuA + (0.02f * bjA) * RdA
               + costB + (0.05f * bjB) * RuB + (0.02f * bjB) * RdB;
        float tot = row_sum1(lo.x + lo.y);
        if (lh == 0) ws_partial[lp] = tot;
    }
}

// obj[b] = sum_t ws_partial[b*T + t]   (deterministic, tiny)
__global__ __launch_bounds__(64)
void obj_final_kernel(const float* __restrict__ ws_partial, float* __restrict__ out)
{
    const int b = blockIdx.x * 64 + threadIdx.x;
    if (b < B) {
        float s = 0.f;
        #pragma unroll
        for (int t = 0; t < T; ++t) s += ws_partial[b * T + t];
        out[3 * SZ + b] = s;
    }
}

// Fallback (ws too small): recompute obj from outputs, one block per b
__global__ __launch_bounds__(256)
void obj_kernel(const float* __restrict__ bcost, float* __restrict__ out)
{
    const int b = blockIdx.x;
    const float* Ru = out + SZ     + (size_t)b * (G * T);
    const float* Rd = out + 2 * SZ + (size_t)b * (G * T);
    const float* C  = out + 3 * SZ + B + (size_t)b * (G * T);

    float s = 0.f;
    for (int i = threadIdx.x; i < G * T; i += 256) {
        const int g = i / T;
        const float bg = bcost[g];
        s += C[i] + 0.05f * bg * Ru[i] + 0.02f * bg * Rd[i];
    }
    __shared__ float sm[16];
    s = row_sum1(s);                                 // 16-lane row sums
    if ((threadIdx.x & 15) == 0) sm[threadIdx.x >> 4] = s;
    __syncthreads();
    if (threadIdx.x == 0) {
        float tot = 0.f;
        #pragma unroll
        for (int i = 0; i < 16; ++i) tot += sm[i];
        out[3 * SZ + b] = tot;
    }
}

extern "C" void kernel_launch(void* const* d_in, const int* in_sizes, int n_in,
                              void* d_out, int out_size, void* d_ws, size_t ws_size,
                              hipStream_t stream) {
    const float* forecast = (const float*)d_in[0];
    const float* pmin_p   = (const float*)d_in[1];
    const float* pmax_p   = (const float*)d_in[2];
    const float* b_p      = (const float*)d_in[3];
    const float* c_p      = (const float*)d_in[4];
    const int*   niter_p  = (const int*)  d_in[5];
    float* out = (float*)d_out;

    // ||K||_2 analytic for this fixed 0/±1 structure (G=50):
    // K^T K = [[4I+J, I, -I],[I, I+J, 0],[-I, 0, I+J]]; largest eig on the
    // ones-subspace is (105+sqrt(17))/2  ->  L = sqrt((105+sqrt(17))/2)
    const double L = sqrt((105.0 + sqrt(17.0)) * 0.5);
    const float tau = (float)(0.9 / L);   // sigma == tau

    const bool use_ws = (ws_size >= (size_t)NLP * sizeof(float));
    float* wsp = use_ws ? (float*)d_ws : nullptr;

    // 16 lanes/LP, 4 LPs/wave: best instr/LP (~22 wave-instr per LP-iter).
    // 768 waves; the staged DPP reduce is there to raise per-wave busy%.
    pdhg_lp_kernel<<<NLP / 4, 64, 0, stream>>>(forecast, pmin_p, pmax_p,
                                               b_p, c_p, niter_p, out, wsp, tau);
    if (use_ws) {
        obj_final_kernel<<<(B + 63) / 64, 64, 0, stream>>>(wsp, out);
    } else {
        obj_kernel<<<B, 256, 0, stream>>>(b_p, out);
    }
}